// Round 6
// baseline (557.368 us; speedup 1.0000x reference)
//
#include <hip/hip_runtime.h>

typedef __attribute__((ext_vector_type(8))) short bf16x8;
typedef __attribute__((ext_vector_type(4))) float f32x4;

#define MSTRIDE 264   // Rb/Ob row stride in shorts (528B, 16B aligned, bank-balanced)
#define XSTRIDE 392   // Xs row stride in shorts (784B, 16B aligned, bank-balanced)

// Pre-converted transposed weights (bf16, [n][k]) — module-scope device memory,
// rewritten every call by transcvt_all. L2-resident (640 KB total).
__device__ __align__(16) unsigned short g_WQT[256 * 256];
__device__ __align__(16) unsigned short g_WKVT[512 * 384];
__device__ __align__(16) unsigned short g_WOT[256 * 256];

__device__ __forceinline__ float b2f(unsigned short u) {
    union { unsigned int i; float f; } v; v.i = ((unsigned int)u) << 16; return v.f;
}
__device__ __forceinline__ unsigned short f2b(float f) {
    union { float f; unsigned int i; } v; v.f = f;
    unsigned int x = v.i;
    return (unsigned short)((x + 0x7fffu + ((x >> 16) & 1u)) >> 16);  // RNE
}

// One launch transposes+converts all three weight matrices.
// dst[c][r] = bf16(src[r][c]); tiles flattened into blockIdx.x.
__global__ void transcvt_all(const float* __restrict__ wq, const float* __restrict__ wkv,
                             const float* __restrict__ wo,
                             unsigned short* __restrict__ dq, unsigned short* __restrict__ dkv,
                             unsigned short* __restrict__ dwo) {
    __shared__ float tile[32][33];
    const int b = blockIdx.x;
    const float* src; unsigned short* dst; int R, C, bx, by;
    if (b < 64)       { src = wq;  dst = dq;  R = 256; C = 256; bx = b & 7;  by = b >> 3; }
    else if (b < 256) { const int t = b - 64;  src = wkv; dst = dkv; R = 384; C = 512; bx = t & 15; by = t >> 4; }
    else              { const int t = b - 256; src = wo;  dst = dwo; R = 256; C = 256; bx = t & 7;  by = t >> 3; }
    const int c0 = bx * 32, r0 = by * 32;
    const int tx = threadIdx.x, ty = threadIdx.y;   // 32 x 8
#pragma unroll
    for (int i = 0; i < 32; i += 8)
        tile[ty + i][tx] = src[(size_t)(r0 + ty + i) * C + (c0 + tx)];
    __syncthreads();
#pragma unroll
    for (int i = 0; i < 32; i += 8)
        dst[(size_t)(c0 + ty + i) * R + (r0 + tx)] = f2b(tile[tx][ty + i]);
}

// load 8 consecutive f32, convert, store 8 bf16 (16B) to LDS
__device__ __forceinline__ void ld8f(const float* __restrict__ s, unsigned short* dst) {
    const float4 a = *(const float4*)s;
    const float4 b = *(const float4*)(s + 4);
    unsigned short t[8];
    t[0] = f2b(a.x); t[1] = f2b(a.y); t[2] = f2b(a.z); t[3] = f2b(a.w);
    t[4] = f2b(b.x); t[5] = f2b(b.y); t[6] = f2b(b.z); t[7] = f2b(b.w);
    *(uint4*)dst = *(const uint4*)t;
}

// Fully fused temporal attention.
// v7: K+V projection RE-FUSED (single kc loop) at the 32-col/wave slice.
// v6 counters showed LDS port+conflict time ~1/3 of kernel: 8 waves each
// re-read the head-independent X fragments, and the K/V split doubled that.
// Fused: af burst feeds 32 MFMAs (was 16), X LDS reads halve, af-burst
// latency exposures halve. acc = accK[8][2]+accV[8][2] = 128 AGPR + ~100
// VGPR = ~236 < 256 -> still 2 waves/SIMD (the v4-era split was only needed
// at 64-col slices). Softmax moved after the fused loop (accK dies there,
// accV lives to PV). Everything else identical to v6.
__global__ __launch_bounds__(512, 2) void ta_fused(
    const float* __restrict__ node,
    const float* __restrict__ timef,
    const float* __restrict__ edge,
    const float* __restrict__ nbrnode,
    const float* __restrict__ nbrtime,
    const int* __restrict__ nmask,
    const float* __restrict__ bO,
    const float* __restrict__ gam,
    const float* __restrict__ bet,
    float* __restrict__ out)
{
    __shared__ __align__(16) unsigned short Xs[128 * XSTRIDE];  // 100352 B, X bf16 [row][k]
    __shared__ __align__(16) unsigned short Rb[4 * MSTRIDE];    // residual R rows 0..3
    __shared__ __align__(16) unsigned short Ob[4 * MSTRIDE];    // attention out O rows 0..3
    __shared__ int mk[4][32];
    float* lnb = (float*)Xs;    // [4][256] overlay — Xs dead after fused KV loop

    const int gb0  = blockIdx.x * 4;
    const int tid  = threadIdx.x;
    const int w    = tid >> 6;          // wave 0..7 = head 0..7
    const int lane = tid & 63;
    const int l15  = lane & 15;
    const int quad = lane >> 4;
    const int arow = (l15 & 3) * MSTRIDE;   // A-frag row for M=4 GEMMs (C rows 4..15 garbage)

    // mask stride sniff, parallel OR (no serial dependent-load chain)
    int orv = 0;
#pragma unroll
    for (int i = 1; i < 64; i += 2) orv |= nmask[i];
    const bool m64 = (orv == 0);

    if (tid < 128) {              // R rows: concat(node, time) for b=0..3
        const int b = tid >> 5, s = tid & 31;
        if (s < 16) ld8f(node  + (size_t)(gb0 + b) * 128 + s * 8,        &Rb[b * MSTRIDE + s * 8]);
        else        ld8f(timef + (size_t)(gb0 + b) * 128 + (s - 16) * 8, &Rb[b * MSTRIDE + s * 8]);
    } else if (tid < 256) {       // neighbor masks for b=0..3
        const int t = tid - 128, b = t >> 5, n = t & 31;
        const size_t j = (size_t)(gb0 + b) * 32 + n;
        mk[b][n] = m64 ? nmask[2 * j] : nmask[j];
    }
    // ---- stage X = concat(nbr_node, edge, nbr_time) bf16 [128][384], once ----
#pragma unroll
    for (int i = 0; i < 12; i++) {
        const int g  = i * 512 + tid;        // 0..6143
        const int r  = g / 48, c8 = g % 48;  // row 0..127, 8-elem chunk 0..47
        const float* base; int koff;
        if (c8 < 16)      { base = nbrnode; koff = c8 * 8; }
        else if (c8 < 32) { base = edge;    koff = (c8 - 16) * 8; }
        else              { base = nbrtime; koff = (c8 - 32) * 8; }
        ld8f(base + (size_t)(gb0 * 32 + r) * 128 + koff, &Xs[r * XSTRIDE + c8 * 8]);
    }
    __syncthreads();   // barrier #1: Rb/Xs/mk visible to all waves

    // wave w reads rows [32w, 32w+32) of each weight block
    const unsigned short* wq  = g_WQT  + (size_t)(w * 32 + l15) * 256 + quad * 8;
    const unsigned short* wkv = g_WKVT + (size_t)(w * 32 + l15) * 384 + quad * 8;
    const unsigned short* wo  = g_WOT  + (size_t)(w * 32 + l15) * 256 + quad * 8;
    const f32x4 zero4 = {0.0f, 0.0f, 0.0f, 0.0f};

    // ================= Phase Q: Q = R @ W_Q  (M=4, cols 32w..32w+32) ====================
    f32x4 accq[2];
#pragma unroll
    for (int ct = 0; ct < 2; ct++) accq[ct] = zero4;
    {
        bf16x8 bq[2][2];
#pragma unroll
        for (int p = 0; p < 2; p++)
#pragma unroll
            for (int ct = 0; ct < 2; ct++)
                bq[p][ct] = *(const bf16x8*)(wq + (size_t)(ct * 16) * 256 + p * 32);
#pragma unroll
        for (int kc = 0; kc < 8; kc++) {
            const int s = kc & 1;
            const bf16x8 aq = *(const bf16x8*)(&Rb[arow + kc * 32 + quad * 8]);
#pragma unroll
            for (int ct = 0; ct < 2; ct++)
                accq[ct] = __builtin_amdgcn_mfma_f32_16x16x32_bf16(aq, bq[s][ct], accq[ct], 0, 0, 0);
            if (kc + 2 < 8) {
#pragma unroll
                for (int ct = 0; ct < 2; ct++)
                    bq[s][ct] = *(const bf16x8*)(wq + (size_t)(ct * 16) * 256 + (kc + 2) * 32);
            }
        }
    }

    // ========== fused KV: K,V = X @ W_KV[:, {32w, 256+32w}]  (128 x 32 each, K=384) =====
    f32x4 accK[8][2], accV[8][2];
#pragma unroll
    for (int rt = 0; rt < 8; rt++)
#pragma unroll
        for (int ct = 0; ct < 2; ct++) { accK[rt][ct] = zero4; accV[rt][ct] = zero4; }
    {
        bf16x8 bK[2][2], bV[2][2];
#pragma unroll
        for (int p = 0; p < 2; p++)
#pragma unroll
            for (int ct = 0; ct < 2; ct++) {
                bK[p][ct] = *(const bf16x8*)(wkv + (size_t)(ct * 16) * 384 + p * 32);
                bV[p][ct] = *(const bf16x8*)(wkv + (size_t)(256 + ct * 16) * 384 + p * 32);
            }
#pragma unroll
        for (int kc = 0; kc < 12; kc++) {
            const int s = kc & 1;
            bf16x8 af[8];
#pragma unroll
            for (int rt = 0; rt < 8; rt++)
                af[rt] = *(const bf16x8*)(&Xs[(rt * 16 + l15) * XSTRIDE + kc * 32 + quad * 8]);
            __builtin_amdgcn_s_setprio(1);
#pragma unroll
            for (int ct = 0; ct < 2; ct++)
#pragma unroll
                for (int rt = 0; rt < 8; rt++) {
                    accK[rt][ct] = __builtin_amdgcn_mfma_f32_16x16x32_bf16(af[rt], bK[s][ct], accK[rt][ct], 0, 0, 0);
                    accV[rt][ct] = __builtin_amdgcn_mfma_f32_16x16x32_bf16(af[rt], bV[s][ct], accV[rt][ct], 0, 0, 0);
                }
            __builtin_amdgcn_s_setprio(0);
            if (kc + 2 < 12) {
#pragma unroll
                for (int ct = 0; ct < 2; ct++) {
                    bK[s][ct] = *(const bf16x8*)(wkv + (size_t)(ct * 16) * 384 + (kc + 2) * 32);
                    bV[s][ct] = *(const bf16x8*)(wkv + (size_t)(256 + ct * 16) * 384 + (kc + 2) * 32);
                }
            }
        }
    }

    // ================= softmax: scores + masked softmax (C-layout) ======================
    // accK: lane holds K[row n = rt*16+quad*4+rg][col = 32w+ct*16+l15]; batch bb = rt>>1.
    float aw[4][2][4];
    const float scl = 0.17677669529663687f;   // 32^-0.5
#pragma unroll
    for (int bb = 0; bb < 4; bb++) {
        float qv[2];
#pragma unroll
        for (int ct = 0; ct < 2; ct++) qv[ct] = __shfl(accq[ct][bb], l15, 64);
        float sv[2][4];
#pragma unroll
        for (int rtl = 0; rtl < 2; rtl++) {
            const int rt = bb * 2 + rtl;
#pragma unroll
            for (int rg = 0; rg < 4; rg++)
                sv[rtl][rg] = accK[rt][0][rg] * qv[0] + accK[rt][1][rg] * qv[1];
        }
#pragma unroll
        for (int m = 1; m <= 8; m <<= 1)
#pragma unroll
            for (int rtl = 0; rtl < 2; rtl++)
#pragma unroll
                for (int rg = 0; rg < 4; rg++)
                    sv[rtl][rg] += __shfl_xor(sv[rtl][rg], m, 64);
        float mx = -3.0e38f;
#pragma unroll
        for (int rtl = 0; rtl < 2; rtl++)
#pragma unroll
            for (int rg = 0; rg < 4; rg++) {
                const int n = rtl * 16 + quad * 4 + rg;
                sv[rtl][rg] = (mk[bb][n] != 0) ? sv[rtl][rg] * scl : -1.0e10f;
                mx = fmaxf(mx, sv[rtl][rg]);
            }
        mx = fmaxf(mx, __shfl_xor(mx, 16, 64));
        mx = fmaxf(mx, __shfl_xor(mx, 32, 64));
        float sum = 0.0f;
#pragma unroll
        for (int rtl = 0; rtl < 2; rtl++)
#pragma unroll
            for (int rg = 0; rg < 4; rg++) {
                const float e = __expf(sv[rtl][rg] - mx);
                aw[bb][rtl][rg] = e;
                sum += e;
            }
        sum += __shfl_xor(sum, 16, 64);
        sum += __shfl_xor(sum, 32, 64);
        const float inv = 1.0f / sum;
#pragma unroll
        for (int rtl = 0; rtl < 2; rtl++)
#pragma unroll
            for (int rg = 0; rg < 4; rg++)
                aw[bb][rtl][rg] *= inv;
    }

    // ================= PV: O = A @ V  (reduce over rows n -> quad shuffles) =============
#pragma unroll
    for (int bb = 0; bb < 4; bb++)
#pragma unroll
        for (int ct = 0; ct < 2; ct++) {
            float o = 0.0f;
#pragma unroll
            for (int rtl = 0; rtl < 2; rtl++)
#pragma unroll
                for (int rg = 0; rg < 4; rg++)
                    o += aw[bb][rtl][rg] * accV[bb * 2 + rtl][ct][rg];
            o += __shfl_xor(o, 16, 64);
            o += __shfl_xor(o, 32, 64);
            if (quad == 0) {
                const int col = w * 32 + ct * 16 + l15;
                Ob[bb * MSTRIDE + col] = f2b(o);
            }
        }
    __syncthreads();   // barrier #2: all waves' O columns visible (KV loop done -> Xs dead)

    // ================= O-proj: out = O @ W_O + b_O + R, then LayerNorm ==================
    f32x4 acco[2];
#pragma unroll
    for (int ct = 0; ct < 2; ct++) acco[ct] = zero4;
    {
        bf16x8 bo[2][2];
#pragma unroll
        for (int p = 0; p < 2; p++)
#pragma unroll
            for (int ct = 0; ct < 2; ct++)
                bo[p][ct] = *(const bf16x8*)(wo + (size_t)(ct * 16) * 256 + p * 32);
#pragma unroll
        for (int kc = 0; kc < 8; kc++) {
            const int s = kc & 1;
            const bf16x8 ao = *(const bf16x8*)(&Ob[arow + kc * 32 + quad * 8]);
#pragma unroll
            for (int ct = 0; ct < 2; ct++)
                acco[ct] = __builtin_amdgcn_mfma_f32_16x16x32_bf16(ao, bo[s][ct], acco[ct], 0, 0, 0);
            if (kc + 2 < 8) {
#pragma unroll
                for (int ct = 0; ct < 2; ct++)
                    bo[s][ct] = *(const bf16x8*)(wo + (size_t)(ct * 16) * 256 + (kc + 2) * 32);
            }
        }
    }
    if (quad == 0) {
#pragma unroll
        for (int ct = 0; ct < 2; ct++) {
#pragma unroll
            for (int r = 0; r < 4; r++) {
                const int col = w * 32 + ct * 16 + l15;
                lnb[r * 256 + col] = acco[ct][r] + bO[col] + b2f(Rb[r * MSTRIDE + col]);
            }
        }
    }
    __syncthreads();   // barrier #3: lnb complete

    if (w < 4) {   // wave w -> batch row w
        const int bb = w;
        float x[4]; float s = 0.0f;
#pragma unroll
        for (int i = 0; i < 4; i++) { x[i] = lnb[bb * 256 + lane + i * 64]; s += x[i]; }
#pragma unroll
        for (int m = 1; m <= 32; m <<= 1) s += __shfl_xor(s, m, 64);
        const float mu = s * (1.0f / 256.0f);
        float s2 = 0.0f;
#pragma unroll
        for (int i = 0; i < 4; i++) { const float d = x[i] - mu; s2 += d * d; }
#pragma unroll
        for (int m = 1; m <= 32; m <<= 1) s2 += __shfl_xor(s2, m, 64);
        const float rstd = rsqrtf(s2 * (1.0f / 256.0f) + 1e-5f);
#pragma unroll
        for (int i = 0; i < 4; i++) {
            const int col = lane + i * 64;
            out[(size_t)(gb0 + bb) * 256 + col] =
                (x[i] - mu) * rstd * gam[col] + bet[col];
        }
    }
}

extern "C" void kernel_launch(void* const* d_in, const int* in_sizes, int n_in,
                              void* d_out, int out_size, void* d_ws, size_t ws_size,
                              hipStream_t stream) {
    const float* node    = (const float*)d_in[0];
    const float* timef   = (const float*)d_in[1];
    const float* edge    = (const float*)d_in[2];
    const float* nbrnode = (const float*)d_in[3];
    const float* nbrtime = (const float*)d_in[4];
    const int*   nmask   = (const int*)d_in[5];
    const float* W_Q     = (const float*)d_in[6];
    const float* W_KV    = (const float*)d_in[7];
    const float* W_O     = (const float*)d_in[8];
    const float* bO      = (const float*)d_in[9];
    const float* gam     = (const float*)d_in[10];
    const float* bet     = (const float*)d_in[11];

    unsigned short *wqt, *wkvt, *wot;
    hipGetSymbolAddress((void**)&wqt,  HIP_SYMBOL(g_WQT));
    hipGetSymbolAddress((void**)&wkvt, HIP_SYMBOL(g_WKVT));
    hipGetSymbolAddress((void**)&wot,  HIP_SYMBOL(g_WOT));

    transcvt_all<<<320, dim3(32, 8), 0, stream>>>(W_Q, W_KV, W_O, wqt, wkvt, wot);

    ta_fused<<<2048, 512, 0, stream>>>(node, timef, edge, nbrnode, nbrtime, nmask,
                                       bO, gam, bet, (float*)d_out);
}